// Round 5
// baseline (209.074 us; speedup 1.0000x reference)
//
#include <hip/hip_runtime.h>
#include <hip/hip_bf16.h>

#define DEV __device__ __forceinline__

typedef __attribute__((ext_vector_type(4))) float f32x4;
typedef __bf16 bf16x8 __attribute__((ext_vector_type(8)));

static DEV unsigned short f2bf(float f) {
    union { float f; unsigned u; } x; x.f = f;
    unsigned r = x.u + 0x7fffu + ((x.u >> 16) & 1u);
    return (unsigned short)(r >> 16);
}

static DEV f32x4 zero4() { f32x4 v; v[0] = 0.f; v[1] = 0.f; v[2] = 0.f; v[3] = 0.f; return v; }

#define GL1(p) ((const __attribute__((address_space(1))) void*)(p))
#define LDS3(p) ((__attribute__((address_space(3))) void*)(p))

// ---------------- fused prep: x->bf16, Wa^T->bf16, Wp^T->bf16 ----------------

__global__ __launch_bounds__(256) void k_prep(
    const float* __restrict__ x, unsigned short* __restrict__ xb,
    const float* __restrict__ Wa, unsigned short* __restrict__ WaT,
    const float* __restrict__ Wp, unsigned short* __restrict__ WpT)
{
    int i = blockIdx.x * 256 + threadIdx.x;
    if (i < 3145728) {
        float4 v = reinterpret_cast<const float4*>(x)[i];
        ushort4 o;
        o.x = f2bf(v.x); o.y = f2bf(v.y); o.z = f2bf(v.z); o.w = f2bf(v.w);
        reinterpret_cast<ushort4*>(xb)[i] = o;
    } else if (i < 3145728 + 442368) {
        int j = i - 3145728;
        int n = j / 384, k = j - n * 384;
        WaT[j] = f2bf(Wa[(size_t)k * 1152 + n]);
    } else if (i < 3145728 + 442368 + 147456) {
        int j = i - (3145728 + 442368);
        int n = j / 384, k = j - n * 384;
        WpT[j] = f2bf(Wp[(size_t)k * 384 + n]);
    }
}

// ---------------- GEMM: C[M,N] = A[M,384] * B^T  (B stored [N][384]) ----------------
// m97-style: global_load_lds width-16 staging into linear LDS, 2-barrier K-loop.

template <int EPI>
__global__ __launch_bounds__(256) void k_gemm(
    const unsigned short* __restrict__ A,
    const unsigned short* __restrict__ B,
    unsigned short* __restrict__ Qb, unsigned short* __restrict__ Kb, unsigned short* __restrict__ Vtb,
    const float* __restrict__ bias, float* __restrict__ Out)
{
    const int K = 384;
    __shared__ unsigned short lA[128][64];
    __shared__ unsigned short lB[128][64];

    int tid = threadIdx.x;
    int m0 = blockIdx.x * 128;
    int n0 = blockIdx.y * 128;
    int w = tid >> 6, lane = tid & 63;
    int wm = (w >> 1) * 64, wn = (w & 1) * 64;
    int lr = lane & 15, lg = lane >> 4;

    f32x4 acc[4][4];
#pragma unroll
    for (int i = 0; i < 4; i++)
#pragma unroll
        for (int j = 0; j < 4; j++) acc[i][j] = zero4();

    const int lrow = lane >> 3;
    const int lcol = (lane & 7) * 8;

    for (int kb = 0; kb < K; kb += 64) {
        __syncthreads();
#pragma unroll
        for (int c = 0; c < 4; ++c) {
            int rb = (w * 4 + c) * 8;
            __builtin_amdgcn_global_load_lds(GL1(&A[(size_t)(m0 + rb + lrow) * K + kb + lcol]),
                                             LDS3(&lA[rb][0]), 16, 0, 0);
            __builtin_amdgcn_global_load_lds(GL1(&B[(size_t)(n0 + rb + lrow) * K + kb + lcol]),
                                             LDS3(&lB[rb][0]), 16, 0, 0);
        }
        __syncthreads();

        bf16x8 af[4][2], bfr[4][2];
#pragma unroll
        for (int kc = 0; kc < 2; ++kc) {
#pragma unroll
            for (int t = 0; t < 4; ++t) {
                af[t][kc]  = *(const bf16x8*)&lA[wm + t * 16 + lr][kc * 32 + lg * 8];
                bfr[t][kc] = *(const bf16x8*)&lB[wn + t * 16 + lr][kc * 32 + lg * 8];
            }
        }
#pragma unroll
        for (int kc = 0; kc < 2; ++kc)
#pragma unroll
            for (int mt = 0; mt < 4; ++mt)
#pragma unroll
                for (int nt = 0; nt < 4; ++nt)
                    acc[mt][nt] = __builtin_amdgcn_mfma_f32_16x16x32_bf16(af[mt][kc], bfr[nt][kc], acc[mt][nt], 0, 0, 0);
    }

#pragma unroll
    for (int mt = 0; mt < 4; ++mt) {
#pragma unroll
        for (int nt = 0; nt < 4; ++nt) {
#pragma unroll
            for (int r = 0; r < 4; ++r) {
                int row = m0 + wm + mt * 16 + lg * 4 + r;
                int col = n0 + wn + nt * 16 + lr;
                float v = acc[mt][nt][r];
                if (EPI == 0) {
                    int which = col / 384;
                    int c = col - which * 384;
                    int hh = c >> 6, d = c & 63;
                    int bb = row >> 10, t = row & 1023;
                    size_t bh = (size_t)bb * 6 + hh;
                    // Q pre-scaled by 1/sqrt(64) * log2(e) for exp2-domain softmax
                    if (which == 0)      Qb[(bh * 1024 + t) * 64 + d] = f2bf(v * 0.18033688f);
                    else if (which == 1) Kb[(bh * 1024 + t) * 64 + d] = f2bf(v);
                    else                 Vtb[(bh * 64 + d) * 1024 + t] = f2bf(v);
                } else {
                    Out[(size_t)row * 384 + col] = v + bias[col];
                }
            }
        }
    }
}

// ---------------- flash attention, fixed-max (exp2 domain), no block barriers ----

template <int NTM, bool MASK>
static DEV void attn_tile(
    const bf16x8 (&kf)[4][2], const bf16x8 (&vf)[4][2],
    const bf16x8 (&qf)[2][2], f32x4 (&o)[2][4], float (&ls)[2],
    unsigned short (&lPw)[32][72], int kt, int qw, int lr, int lg)
{
    constexpr int KCM = NTM / 2;

    // S^T = K * Q^T : lane holds col=q(lr), rows=k(lg*4+r) per 16-k subtile
    f32x4 st[2][NTM];
#pragma unroll
    for (int mt = 0; mt < 2; ++mt)
#pragma unroll
        for (int nt = 0; nt < NTM; ++nt) st[mt][nt] = zero4();

#pragma unroll
    for (int kc = 0; kc < 2; ++kc)
#pragma unroll
        for (int mt = 0; mt < 2; ++mt)
#pragma unroll
            for (int nt = 0; nt < NTM; ++nt)
                st[mt][nt] = __builtin_amdgcn_mfma_f32_16x16x32_bf16(kf[nt][kc], qf[mt][kc], st[mt][nt], 0, 0, 0);

    // exp2 (fixed max), tree-summed rowsum partials, native bf16 pack, vector LDS write
#pragma unroll
    for (int mt = 0; mt < 2; ++mt) {
#pragma unroll
        for (int nt = 0; nt < NTM; ++nt) {
            union { __bf16 h[4]; uint2 u; } pk;
            float e[4];
#pragma unroll
            for (int r = 0; r < 4; ++r) {
                float ev = __builtin_amdgcn_exp2f(st[mt][nt][r]);
                if (MASK) {
                    int kg = kt * 64 + nt * 16 + lg * 4 + r;
                    int qg = qw + mt * 16 + lr;
                    if (kg > qg) ev = 0.f;
                }
                e[r] = ev;
                pk.h[r] = (__bf16)ev;
            }
            ls[mt] += (e[0] + e[1]) + (e[2] + e[3]);
            *(uint2*)&lPw[mt * 16 + lr][nt * 16 + lg * 4] = pk.u;
        }
    }

    // P as A-fragment (wave-private LDS round-trip, no barrier)
    bf16x8 pf[2][KCM];
#pragma unroll
    for (int mt = 0; mt < 2; ++mt)
#pragma unroll
        for (int kc = 0; kc < KCM; ++kc)
            pf[mt][kc] = *(const bf16x8*)&lPw[mt * 16 + lr][kc * 32 + lg * 8];

#pragma unroll
    for (int mt = 0; mt < 2; ++mt)
#pragma unroll
        for (int nt = 0; nt < 4; ++nt)
#pragma unroll
            for (int kc = 0; kc < KCM; ++kc)
                o[mt][nt] = __builtin_amdgcn_mfma_f32_16x16x32_bf16(pf[mt][kc], vf[nt][kc], o[mt][nt], 0, 0, 0);
}

static DEV void attn_tail(bool odd,
    const bf16x8 (&kf)[4][2], const bf16x8 (&vf)[4][2],
    const bf16x8 (&qf)[2][2], f32x4 (&o)[2][4], float (&ls)[2],
    unsigned short (&lPw)[32][72], int kt, int qw, int lr, int lg)
{
    if (odd) attn_tile<4, true>(kf, vf, qf, o, ls, lPw, kt, qw, lr, lg);
    else     attn_tile<2, true>(kf, vf, qf, o, ls, lPw, kt, qw, lr, lg);
}

static DEV void do_step(
    const bf16x8 (&kf)[4][2], const bf16x8 (&vf)[4][2],
    const bf16x8 (&qfA)[2][2], const bf16x8 (&qfB)[2][2],
    f32x4 (&oA)[2][4], f32x4 (&oB)[2][4],
    float (&lsA)[2], float (&lsB)[2],
    unsigned short (&lP0)[32][72], unsigned short (&lP1)[32][72],
    int kt, int qwA, int qwB, int nktA, int nktB, bool oddA, bool oddB, int lr, int lg)
{
    if (kt == nktA - 1) attn_tail(oddA, kf, vf, qfA, oA, lsA, lP0, kt, qwA, lr, lg);
    else                attn_tile<4, false>(kf, vf, qfA, oA, lsA, lP0, kt, qwA, lr, lg);
    if (kt < nktB) {
        if (kt == nktB - 1) attn_tail(oddB, kf, vf, qfB, oB, lsB, lP1, kt, qwB, lr, lg);
        else                attn_tile<4, false>(kf, vf, qfB, oB, lsB, lP1, kt, qwB, lr, lg);
    }
}

static DEV void attn_out(const f32x4 (&o)[2][4], const float (&ls)[2],
                         int qw, int b, int h, int lr, int lg,
                         unsigned short* __restrict__ Y)
{
    float inv[2];
#pragma unroll
    for (int mt = 0; mt < 2; ++mt) {
        float s = ls[mt];
        s += __shfl_xor(s, 16);
        s += __shfl_xor(s, 32);
        inv[mt] = 1.0f / s;
    }
#pragma unroll
    for (int mt = 0; mt < 2; ++mt) {
        float iv[4];
#pragma unroll
        for (int r = 0; r < 4; ++r) iv[r] = __shfl(inv[mt], lg * 4 + r);
#pragma unroll
        for (int nt = 0; nt < 4; ++nt)
#pragma unroll
            for (int r = 0; r < 4; ++r) {
                int qrow = qw + mt * 16 + lg * 4 + r;
                int col = h * 64 + nt * 16 + lr;
                Y[((size_t)b * 1024 + qrow) * 384 + col] = f2bf(o[mt][nt][r] * iv[r]);
            }
    }
}

#define LOADK(dst, KT)                                                                        \
    {                                                                                         \
        _Pragma("unroll") for (int nt = 0; nt < 4; ++nt)                                      \
            _Pragma("unroll") for (int kc = 0; kc < 2; ++kc)                                  \
                dst[nt][kc] = *(const bf16x8*)&Kbase[(size_t)(KT) * 4096 +                    \
                                                     (nt * 16 + lr) * 64 + kc * 32 + lg * 8]; \
    }

#define LOADV(dst, KT)                                                                        \
    {                                                                                         \
        _Pragma("unroll") for (int nt = 0; nt < 4; ++nt)                                      \
            _Pragma("unroll") for (int kc = 0; kc < 2; ++kc)                                  \
                dst[nt][kc] = *(const bf16x8*)&Vbase[(size_t)(nt * 16 + lr) * 1024 +          \
                                                     (KT) * 64 + kc * 32 + lg * 8];           \
    }

// grid (48 bh-groups, 16 qtile-pairs); block 256 = 4 waves; wave w handles bh=bx*4+w,
// q-tiles qtA=16+p and qtB=15-p (uniform 17 tile-steps per wave; K/V loads shared).
// K fragments double-buffered in registers (prefetch 1 tile ahead).
__global__ __launch_bounds__(256, 2) void k_attn(
    const unsigned short* __restrict__ Q,
    const unsigned short* __restrict__ Kp,
    const unsigned short* __restrict__ Vt,
    unsigned short* __restrict__ Y)
{
    __shared__ unsigned short lP[4][2][32][72];

    const int tid = threadIdx.x;
    const int w = tid >> 6, lane = tid & 63;
    const int lr = lane & 15, lg = lane >> 4;
    const int p = blockIdx.y;
    const int qtA = 16 + p, qtB = 15 - p;
    const int bh = blockIdx.x * 4 + w;
    const int b = bh / 6, h = bh - b * 6;
    const int qwA = qtA * 32, qwB = qtB * 32;
    const int nktA = qtA / 2 + 1, nktB = qtB / 2 + 1;
    const bool oddA = qtA & 1, oddB = qtB & 1;
    const size_t bT = (size_t)bh * 1024;

    const unsigned short* Kbase = Kp + bT * 64;
    const unsigned short* Vbase = Vt + (size_t)bh * 64 * 1024;

    bf16x8 qfA[2][2], qfB[2][2];
#pragma unroll
    for (int mt = 0; mt < 2; ++mt)
#pragma unroll
        for (int kc = 0; kc < 2; ++kc) {
            qfA[mt][kc] = *(const bf16x8*)&Q[(bT + qwA + mt * 16 + lr) * 64 + kc * 32 + lg * 8];
            qfB[mt][kc] = *(const bf16x8*)&Q[(bT + qwB + mt * 16 + lr) * 64 + kc * 32 + lg * 8];
        }

    f32x4 oA[2][4], oB[2][4];
    float lsA[2] = {0.f, 0.f}, lsB[2] = {0.f, 0.f};
#pragma unroll
    for (int mt = 0; mt < 2; ++mt)
#pragma unroll
        for (int nt = 0; nt < 4; ++nt) { oA[mt][nt] = zero4(); oB[mt][nt] = zero4(); }

    bf16x8 kf0[4][2], kf1[4][2], vf[4][2];
    LOADK(kf0, 0);

    int kt = 0;
    for (;;) {
        LOADV(vf, kt);
        if (kt + 1 < nktA) LOADK(kf1, kt + 1);
        do_step(kf0, vf, qfA, qfB, oA, oB, lsA, lsB, lP[w][0], lP[w][1],
                kt, qwA, qwB, nktA, nktB, oddA, oddB, lr, lg);
        if (++kt == nktA) break;

        LOADV(vf, kt);
        if (kt + 1 < nktA) LOADK(kf0, kt + 1);
        do_step(kf1, vf, qfA, qfB, oA, oB, lsA, lsB, lP[w][0], lP[w][1],
                kt, qwA, qwB, nktA, nktB, oddA, oddB, lr, lg);
        if (++kt == nktA) break;
    }

    attn_out(oA, lsA, qwA, b, h, lr, lg, Y);
    attn_out(oB, lsB, qwB, b, h, lr, lg, Y);
}

// ---------------- launcher ----------------

extern "C" void kernel_launch(void* const* d_in, const int* in_sizes, int n_in,
                              void* d_out, int out_size, void* d_ws, size_t ws_size,
                              hipStream_t stream)
{
    const float* x  = (const float*)d_in[0];
    const float* Wa = (const float*)d_in[1];
    const float* Wp = (const float*)d_in[2];
    const float* bp = (const float*)d_in[3];
    float* out = (float*)d_out;

    char* ws = (char*)d_ws;
    unsigned short* xb  = (unsigned short*)(ws);              // 25165824 B; reused as Y after attn
    unsigned short* WaT = (unsigned short*)(ws + 25165824);   // 884736 B
    unsigned short* WpT = (unsigned short*)(ws + 26050560);   // 294912 B
    unsigned short* Qb  = (unsigned short*)(ws + 26345472);   // 25165824 B
    unsigned short* Kb  = (unsigned short*)(ws + 51511296);   // 25165824 B
    unsigned short* Vtb = (unsigned short*)(ws + 76677120);   // 25165824 B

    k_prep<<<14592, 256, 0, stream>>>(x, xb, Wa, WaT, Wp, WpT);
    k_gemm<0><<<dim3(256, 9), 256, 0, stream>>>(xb, WaT, Qb, Kb, Vtb, nullptr, nullptr);
    k_attn<<<dim3(48, 16), 256, 0, stream>>>(Qb, Kb, Vtb, xb);
    k_gemm<1><<<dim3(256, 3), 256, 0, stream>>>(xb, WpT, nullptr, nullptr, nullptr, bp, out);
}

// Round 6
// 153.047 us; speedup vs baseline: 1.3661x; 1.3661x over previous
//
#include <hip/hip_runtime.h>
#include <hip/hip_bf16.h>

#define DEV __device__ __forceinline__

typedef __attribute__((ext_vector_type(4))) float f32x4;
typedef __bf16 bf16x8 __attribute__((ext_vector_type(8)));

static DEV unsigned short f2bf(float f) {
    union { float f; unsigned u; } x; x.f = f;
    unsigned r = x.u + 0x7fffu + ((x.u >> 16) & 1u);
    return (unsigned short)(r >> 16);
}

static DEV f32x4 zero4() { f32x4 v; v[0] = 0.f; v[1] = 0.f; v[2] = 0.f; v[3] = 0.f; return v; }

#define GL1(p) ((const __attribute__((address_space(1))) void*)(p))
#define LDS3(p) ((__attribute__((address_space(3))) void*)(p))

// ---------------- fused prep: x->bf16, Wa^T->bf16, Wp^T->bf16 ----------------

__global__ __launch_bounds__(256) void k_prep(
    const float* __restrict__ x, unsigned short* __restrict__ xb,
    const float* __restrict__ Wa, unsigned short* __restrict__ WaT,
    const float* __restrict__ Wp, unsigned short* __restrict__ WpT)
{
    int i = blockIdx.x * 256 + threadIdx.x;
    if (i < 3145728) {
        float4 v = reinterpret_cast<const float4*>(x)[i];
        ushort4 o;
        o.x = f2bf(v.x); o.y = f2bf(v.y); o.z = f2bf(v.z); o.w = f2bf(v.w);
        reinterpret_cast<ushort4*>(xb)[i] = o;
    } else if (i < 3145728 + 442368) {
        int j = i - 3145728;
        int n = j / 384, k = j - n * 384;
        WaT[j] = f2bf(Wa[(size_t)k * 1152 + n]);
    } else if (i < 3145728 + 442368 + 147456) {
        int j = i - (3145728 + 442368);
        int n = j / 384, k = j - n * 384;
        WpT[j] = f2bf(Wp[(size_t)k * 384 + n]);
    }
}

// ---------------- GEMM: C[M,N] = A[M,384] * B^T  (B stored [N][384]) ----------------
// EPI==0: QKV epilogue -> fragment-major Qf/Kf/Vf (see k_attn for layouts)
// EPI==1: out = acc + bias, f32

template <int EPI>
__global__ __launch_bounds__(256) void k_gemm(
    const unsigned short* __restrict__ A,
    const unsigned short* __restrict__ B,
    unsigned short* __restrict__ Qb, unsigned short* __restrict__ Kb, unsigned short* __restrict__ Vtb,
    const float* __restrict__ bias, float* __restrict__ Out)
{
    const int K = 384;
    __shared__ unsigned short lA[128][64];
    __shared__ unsigned short lB[128][64];

    int tid = threadIdx.x;
    int m0 = blockIdx.x * 128;
    int n0 = blockIdx.y * 128;
    int w = tid >> 6, lane = tid & 63;
    int wm = (w >> 1) * 64, wn = (w & 1) * 64;
    int lr = lane & 15, lg = lane >> 4;

    f32x4 acc[4][4];
#pragma unroll
    for (int i = 0; i < 4; i++)
#pragma unroll
        for (int j = 0; j < 4; j++) acc[i][j] = zero4();

    const int lrow = lane >> 3;
    const int lcol = (lane & 7) * 8;

    for (int kb = 0; kb < K; kb += 64) {
        __syncthreads();
#pragma unroll
        for (int c = 0; c < 4; ++c) {
            int rb = (w * 4 + c) * 8;
            __builtin_amdgcn_global_load_lds(GL1(&A[(size_t)(m0 + rb + lrow) * K + kb + lcol]),
                                             LDS3(&lA[rb][0]), 16, 0, 0);
            __builtin_amdgcn_global_load_lds(GL1(&B[(size_t)(n0 + rb + lrow) * K + kb + lcol]),
                                             LDS3(&lB[rb][0]), 16, 0, 0);
        }
        __syncthreads();

        bf16x8 af[4][2], bfr[4][2];
#pragma unroll
        for (int kc = 0; kc < 2; ++kc) {
#pragma unroll
            for (int t = 0; t < 4; ++t) {
                af[t][kc]  = *(const bf16x8*)&lA[wm + t * 16 + lr][kc * 32 + lg * 8];
                bfr[t][kc] = *(const bf16x8*)&lB[wn + t * 16 + lr][kc * 32 + lg * 8];
            }
        }
#pragma unroll
        for (int kc = 0; kc < 2; ++kc)
#pragma unroll
            for (int mt = 0; mt < 4; ++mt)
#pragma unroll
                for (int nt = 0; nt < 4; ++nt)
                    acc[mt][nt] = __builtin_amdgcn_mfma_f32_16x16x32_bf16(af[mt][kc], bfr[nt][kc], acc[mt][nt], 0, 0, 0);
    }

#pragma unroll
    for (int mt = 0; mt < 4; ++mt) {
#pragma unroll
        for (int nt = 0; nt < 4; ++nt) {
#pragma unroll
            for (int r = 0; r < 4; ++r) {
                int row = m0 + wm + mt * 16 + lg * 4 + r;
                int col = n0 + wn + nt * 16 + lr;
                float v = acc[mt][nt][r];
                if (EPI == 0) {
                    int which = col / 384;
                    int c = col - which * 384;
                    int hh = c >> 6, d = c & 63;
                    int bb = row >> 10, t = row & 1023;
                    size_t bh = (size_t)bb * 6 + hh;
                    if (which == 0) {
                        // Qf[bh][qt][mt][kc][lane][8]; lane = (t&15) + 16*((d>>3)&3)
                        int qt = t >> 5, fmt = (t >> 4) & 1;
                        int kc = (d >> 5) & 1, e = d & 7;
                        int ln = (t & 15) + 16 * ((d >> 3) & 3);
                        // pre-scaled by 1/sqrt(64) * log2(e) for exp2-domain softmax
                        Qb[((((bh * 32 + qt) * 2 + fmt) * 2 + kc) * 64 + ln) * 8 + e] = f2bf(v * 0.18033688f);
                    } else if (which == 1) {
                        // Kf[bh][kt][nt][kc][lane][8]; lane = (t&15) + 16*((d>>3)&3)
                        int ktt = t >> 6, fnt = (t >> 4) & 3;
                        int kc = (d >> 5) & 1, e = d & 7;
                        int ln = (t & 15) + 16 * ((d >> 3) & 3);
                        Kb[((((bh * 16 + ktt) * 4 + fnt) * 2 + kc) * 64 + ln) * 8 + e] = f2bf(v);
                    } else {
                        // Vf[bh][kt][nt_d][kc][lane][8]; k=t: lane = (d&15) + 16*((t>>3)&3)
                        int ktt = t >> 6, kc = (t >> 5) & 1, e = t & 7;
                        int fnt = d >> 4;
                        int ln = (d & 15) + 16 * ((t >> 3) & 3);
                        Vtb[((((bh * 16 + ktt) * 4 + fnt) * 2 + kc) * 64 + ln) * 8 + e] = f2bf(v);
                    }
                } else {
                    Out[(size_t)row * 384 + col] = v + bias[col];
                }
            }
        }
    }
}

// ---------------- flash attention, fixed-max (exp2), LDS-staged shared K/V ------
// Block = 1 bh, 4 waves = qtiles {4g..4g+3}. K/V tiles DMA'd via global_load_lds
// (double-buffered, fragment-major -> all LDS accesses linear & conflict-free).

template <int NTM, bool MASK>
static DEV void attn_tile(
    const unsigned short* lKt, const unsigned short* lVt, unsigned short* lPw,
    const bf16x8 (&qf)[2][2], f32x4 (&o)[2][4], float (&ls)[2],
    int kt, int qw, int lane)
{
    constexpr int KCM = NTM / 2;
    const int lr = lane & 15, lg = lane >> 4;

    bf16x8 kf[NTM][2];
#pragma unroll
    for (int nt = 0; nt < NTM; ++nt)
#pragma unroll
        for (int kc = 0; kc < 2; ++kc)
            kf[nt][kc] = *(const bf16x8*)&lKt[(nt * 2 + kc) * 512 + lane * 8];

    bf16x8 vf[4][KCM];
#pragma unroll
    for (int nt = 0; nt < 4; ++nt)
#pragma unroll
        for (int kc = 0; kc < KCM; ++kc)
            vf[nt][kc] = *(const bf16x8*)&lVt[(nt * 2 + kc) * 512 + lane * 8];

    // S^T = K * Q^T : lane holds q = mt*16+lr, k = nt*16+lg*4+r
    f32x4 st[2][NTM];
#pragma unroll
    for (int mt = 0; mt < 2; ++mt)
#pragma unroll
        for (int nt = 0; nt < NTM; ++nt) st[mt][nt] = zero4();

#pragma unroll
    for (int kc = 0; kc < 2; ++kc)
#pragma unroll
        for (int mt = 0; mt < 2; ++mt)
#pragma unroll
            for (int nt = 0; nt < NTM; ++nt)
                st[mt][nt] = __builtin_amdgcn_mfma_f32_16x16x32_bf16(kf[nt][kc], qf[mt][kc], st[mt][nt], 0, 0, 0);

    // exp2 (fixed max), tree rowsum partials, pack bf16, write P in FRAGMENT layout
#pragma unroll
    for (int mt = 0; mt < 2; ++mt) {
#pragma unroll
        for (int nt = 0; nt < NTM; ++nt) {
            union { __bf16 hh[4]; uint2 u; } pk;
            float e[4];
#pragma unroll
            for (int r = 0; r < 4; ++r) {
                float ev = __builtin_amdgcn_exp2f(st[mt][nt][r]);
                if (MASK) {
                    int kg = kt * 64 + nt * 16 + lg * 4 + r;
                    int qg = qw + mt * 16 + lr;
                    if (kg > qg) ev = 0.f;
                }
                e[r] = ev;
                pk.hh[r] = (__bf16)ev;
            }
            ls[mt] += (e[0] + e[1]) + (e[2] + e[3]);
            // P[q][k] -> A-fragment slot: kc=nt>>1, lane'=lr+16*((nt&1)*2+(lg>>1)), e'=(lg&1)*4+r
            int ln2 = lr + 16 * ((nt & 1) * 2 + (lg >> 1));
            *(uint2*)&lPw[(mt * 2 + (nt >> 1)) * 512 + ln2 * 8 + (lg & 1) * 4] = pk.u;
        }
    }

    bf16x8 pf[2][KCM];
#pragma unroll
    for (int mt = 0; mt < 2; ++mt)
#pragma unroll
        for (int kc = 0; kc < KCM; ++kc)
            pf[mt][kc] = *(const bf16x8*)&lPw[(mt * 2 + kc) * 512 + lane * 8];

#pragma unroll
    for (int mt = 0; mt < 2; ++mt)
#pragma unroll
        for (int nt = 0; nt < 4; ++nt)
#pragma unroll
            for (int kc = 0; kc < KCM; ++kc)
                o[mt][nt] = __builtin_amdgcn_mfma_f32_16x16x32_bf16(pf[mt][kc], vf[nt][kc], o[mt][nt], 0, 0, 0);
}

__global__ __launch_bounds__(256, 3) void k_attn(
    const unsigned short* __restrict__ Qf,
    const unsigned short* __restrict__ Kf,
    const unsigned short* __restrict__ Vf,
    unsigned short* __restrict__ Y)
{
    __shared__ unsigned short lK[2][4096];
    __shared__ unsigned short lV[2][4096];
    __shared__ unsigned short lPf[4][2048];

    const int tid = threadIdx.x;
    const int w = tid >> 6, lane = tid & 63;
    const int lr = lane & 15, lg = lane >> 4;
    const int bh = blockIdx.x;
    const int g = 7 - blockIdx.y;            // heavy groups dispatched first
    const int qt = 4 * g + w;
    const int qw = qt * 32;
    const int nkt = qt / 2 + 1;
    const int nsteps = 2 * g + 2;
    const int b = bh / 6, h = bh - b * 6;

    const unsigned short* Kbh = Kf + (size_t)bh * 65536;
    const unsigned short* Vbh = Vf + (size_t)bh * 65536;

    bf16x8 qf[2][2];
#pragma unroll
    for (int mt = 0; mt < 2; ++mt)
#pragma unroll
        for (int kc = 0; kc < 2; ++kc)
            qf[mt][kc] = *(const bf16x8*)&Qf[((((size_t)bh * 32 + qt) * 2 + mt) * 2 + kc) * 512 + lane * 8];

    f32x4 o[2][4];
    float ls[2] = {0.f, 0.f};
#pragma unroll
    for (int mt = 0; mt < 2; ++mt)
#pragma unroll
        for (int nt = 0; nt < 4; ++nt) o[mt][nt] = zero4();

    // prologue stage: tile 0 -> buf 0 (each wave stages its 2KB of K and V)
#pragma unroll
    for (int i = 0; i < 2; ++i) {
        __builtin_amdgcn_global_load_lds(GL1(Kbh + (size_t)w * 1024 + i * 512 + lane * 8),
                                         LDS3(&lK[0][w * 1024 + i * 512]), 16, 0, 0);
        __builtin_amdgcn_global_load_lds(GL1(Vbh + (size_t)w * 1024 + i * 512 + lane * 8),
                                         LDS3(&lV[0][w * 1024 + i * 512]), 16, 0, 0);
    }

    for (int kt = 0; kt < nsteps; ++kt) {
        __syncthreads();   // drains vmcnt -> buf[kt&1] ready; lgkm -> prev reads done
        if (kt + 1 < nsteps) {
            int nb = (kt + 1) & 1;
#pragma unroll
            for (int i = 0; i < 2; ++i) {
                __builtin_amdgcn_global_load_lds(GL1(Kbh + (size_t)(kt + 1) * 4096 + w * 1024 + i * 512 + lane * 8),
                                                 LDS3(&lK[nb][w * 1024 + i * 512]), 16, 0, 0);
                __builtin_amdgcn_global_load_lds(GL1(Vbh + (size_t)(kt + 1) * 4096 + w * 1024 + i * 512 + lane * 8),
                                                 LDS3(&lV[nb][w * 1024 + i * 512]), 16, 0, 0);
            }
        }
        if (kt < nkt) {
            const unsigned short* lKt = lK[kt & 1];
            const unsigned short* lVt = lV[kt & 1];
            if (kt == nkt - 1) {
                if (qt & 1) attn_tile<4, true>(lKt, lVt, lPf[w], qf, o, ls, kt, qw, lane);
                else        attn_tile<2, true>(lKt, lVt, lPf[w], qf, o, ls, kt, qw, lane);
            } else {
                attn_tile<4, false>(lKt, lVt, lPf[w], qf, o, ls, kt, qw, lane);
            }
        }
    }

    // deferred row-sum reduction + output
    float inv[2];
#pragma unroll
    for (int mt = 0; mt < 2; ++mt) {
        float s = ls[mt];
        s += __shfl_xor(s, 16);
        s += __shfl_xor(s, 32);
        inv[mt] = 1.0f / s;
    }
#pragma unroll
    for (int mt = 0; mt < 2; ++mt) {
        float iv[4];
#pragma unroll
        for (int r = 0; r < 4; ++r) iv[r] = __shfl(inv[mt], lg * 4 + r);
#pragma unroll
        for (int nt = 0; nt < 4; ++nt)
#pragma unroll
            for (int r = 0; r < 4; ++r) {
                int qrow = qw + mt * 16 + lg * 4 + r;
                int col = h * 64 + nt * 16 + lr;
                Y[((size_t)b * 1024 + qrow) * 384 + col] = f2bf(o[mt][nt][r] * iv[r]);
            }
    }
}

// ---------------- launcher ----------------

extern "C" void kernel_launch(void* const* d_in, const int* in_sizes, int n_in,
                              void* d_out, int out_size, void* d_ws, size_t ws_size,
                              hipStream_t stream)
{
    const float* x  = (const float*)d_in[0];
    const float* Wa = (const float*)d_in[1];
    const float* Wp = (const float*)d_in[2];
    const float* bp = (const float*)d_in[3];
    float* out = (float*)d_out;

    char* ws = (char*)d_ws;
    unsigned short* xb  = (unsigned short*)(ws);              // 25165824 B; reused as Y after attn
    unsigned short* WaT = (unsigned short*)(ws + 25165824);   // 884736 B
    unsigned short* WpT = (unsigned short*)(ws + 26050560);   // 294912 B
    unsigned short* Qb  = (unsigned short*)(ws + 26345472);   // 25165824 B (fragment-major)
    unsigned short* Kb  = (unsigned short*)(ws + 51511296);   // 25165824 B (fragment-major)
    unsigned short* Vtb = (unsigned short*)(ws + 76677120);   // 25165824 B (fragment-major)

    k_prep<<<14592, 256, 0, stream>>>(x, xb, Wa, WaT, Wp, WpT);
    k_gemm<0><<<dim3(256, 9), 256, 0, stream>>>(xb, WaT, Qb, Kb, Vtb, nullptr, nullptr);
    k_attn<<<dim3(192, 8), 256, 0, stream>>>(Qb, Kb, Vtb, xb);
    k_gemm<1><<<dim3(256, 3), 256, 0, stream>>>(xb, WpT, nullptr, nullptr, nullptr, bp, out);
}

// Round 8
// 125.133 us; speedup vs baseline: 1.6708x; 1.2231x over previous
//
#include <hip/hip_runtime.h>
#include <hip/hip_bf16.h>

#define DEV __device__ __forceinline__

typedef __attribute__((ext_vector_type(4))) float f32x4;
typedef __bf16 bf16x8 __attribute__((ext_vector_type(8)));

static DEV unsigned short f2bf(float f) {
    union { float f; unsigned u; } x; x.f = f;
    unsigned r = x.u + 0x7fffu + ((x.u >> 16) & 1u);
    return (unsigned short)(r >> 16);
}

static DEV f32x4 zero4() { f32x4 v; v[0] = 0.f; v[1] = 0.f; v[2] = 0.f; v[3] = 0.f; return v; }

#define GL1(p) ((const __attribute__((address_space(1))) void*)(p))
#define LDS3(p) ((__attribute__((address_space(3))) void*)(p))

// ---------------- fused prep: x->bf16, Wa^T->bf16, Wp^T->bf16 ----------------

__global__ __launch_bounds__(256) void k_prep(
    const float* __restrict__ x, unsigned short* __restrict__ xb,
    const float* __restrict__ Wa, unsigned short* __restrict__ WaT,
    const float* __restrict__ Wp, unsigned short* __restrict__ WpT)
{
    int i = blockIdx.x * 256 + threadIdx.x;
    if (i < 3145728) {
        float4 v = reinterpret_cast<const float4*>(x)[i];
        ushort4 o;
        o.x = f2bf(v.x); o.y = f2bf(v.y); o.z = f2bf(v.z); o.w = f2bf(v.w);
        reinterpret_cast<ushort4*>(xb)[i] = o;
    } else if (i < 3145728 + 442368) {
        int j = i - 3145728;
        int n = j / 384, k = j - n * 384;
        WaT[j] = f2bf(Wa[(size_t)k * 1152 + n]);
    } else if (i < 3145728 + 442368 + 147456) {
        int j = i - (3145728 + 442368);
        int n = j / 384, k = j - n * 384;
        WpT[j] = f2bf(Wp[(size_t)k * 384 + n]);
    }
}

// ---------------- GEMM main loop (shared): C-tile = A[128,384] * B^T[128,384] ----
// global_load_lds width-16 staging; source-granule XOR-swizzle paired with
// read-side XOR (rule #21: both-sides-or-neither) -> conflict-free ds_read_b128.
// SWAP=0: acc[mt][nt] holds (4 rows t, 1 col)   [rows of C]
// SWAP=1: acc[mt][nt] holds (1 row t, 4 cols)   [operands swapped]

template <int SWAP>
static DEV void gemm_mainloop(
    const unsigned short* __restrict__ A,
    const unsigned short* __restrict__ B,
    int m0, int n0, int tid,
    f32x4 (&acc)[4][4],
    unsigned short (&lA)[128][64], unsigned short (&lB)[128][64])
{
    const int K = 384;
    const int w = tid >> 6, lane = tid & 63;
    const int wm = (w >> 1) * 64, wn = (w & 1) * 64;
    const int lr = lane & 15, lg = lane >> 4;
    const int lrow = lane >> 3;                     // dest row within 8-row chunk
    const int lcol = ((lane & 7) ^ lrow) * 8;       // pre-swizzled SOURCE granule

    for (int kb = 0; kb < K; kb += 64) {
        __syncthreads();
#pragma unroll
        for (int c = 0; c < 4; ++c) {
            int rb = (w * 4 + c) * 8;
            __builtin_amdgcn_global_load_lds(GL1(&A[(size_t)(m0 + rb + lrow) * K + kb + lcol]),
                                             LDS3(&lA[rb][0]), 16, 0, 0);
            __builtin_amdgcn_global_load_lds(GL1(&B[(size_t)(n0 + rb + lrow) * K + kb + lcol]),
                                             LDS3(&lB[rb][0]), 16, 0, 0);
        }
        __syncthreads();

        bf16x8 af[4][2], bfr[4][2];
#pragma unroll
        for (int kc = 0; kc < 2; ++kc) {
#pragma unroll
            for (int t = 0; t < 4; ++t) {
                int ga = ((kc * 4 + lg) ^ (lr & 7)) * 8;   // read-side XOR (same involution)
                af[t][kc]  = *(const bf16x8*)&lA[wm + t * 16 + lr][ga];
                bfr[t][kc] = *(const bf16x8*)&lB[wn + t * 16 + lr][ga];
            }
        }
#pragma unroll
        for (int kc = 0; kc < 2; ++kc)
#pragma unroll
            for (int mt = 0; mt < 4; ++mt)
#pragma unroll
                for (int nt = 0; nt < 4; ++nt)
                    acc[mt][nt] = SWAP
                        ? __builtin_amdgcn_mfma_f32_16x16x32_bf16(bfr[nt][kc], af[mt][kc], acc[mt][nt], 0, 0, 0)
                        : __builtin_amdgcn_mfma_f32_16x16x32_bf16(af[mt][kc], bfr[nt][kc], acc[mt][nt], 0, 0, 0);
    }
}

// ---------------- QKV GEMM: fragment-major Q/K/V epilogues, packed 8B stores ----
// Column-blocks 0-5 are pure Q/K (swapped orientation: thread = 4 consecutive d);
// blocks 6-8 are pure V (original orientation: thread = 4 consecutive t).

__global__ __launch_bounds__(256) void k_gemm_qkv(
    const unsigned short* __restrict__ A,
    const unsigned short* __restrict__ B,
    unsigned short* __restrict__ Qb, unsigned short* __restrict__ Kb,
    unsigned short* __restrict__ Vb)
{
    __shared__ unsigned short lA[128][64];
    __shared__ unsigned short lB[128][64];

    const int tid = threadIdx.x;
    const int m0 = blockIdx.x * 128, n0 = blockIdx.y * 128;
    const int w = tid >> 6, lane = tid & 63;
    const int wm = (w >> 1) * 64, wn = (w & 1) * 64;
    const int lr = lane & 15, lg = lane >> 4;

    f32x4 acc[4][4];
#pragma unroll
    for (int i = 0; i < 4; i++)
#pragma unroll
        for (int j = 0; j < 4; j++) acc[i][j] = zero4();

    if (blockIdx.y < 6) {
        gemm_mainloop<1>(A, B, m0, n0, tid, acc, lA, lB);
        const int which = blockIdx.y / 3;       // 0=Q, 1=K
#pragma unroll
        for (int mt = 0; mt < 4; ++mt) {
            int row = m0 + wm + mt * 16 + lr;
            int bb = row >> 10, tloc = row & 1023;
#pragma unroll
            for (int nt = 0; nt < 4; ++nt) {
                int col = n0 + wn + nt * 16 + lg * 4;
                int c = col - which * 384;
                int hh = c >> 6, d0 = c & 63;
                size_t bh = (size_t)bb * 6 + hh;
                int kc = (d0 >> 5) & 1;
                int ln = (tloc & 15) + 16 * ((d0 >> 3) & 3);
                int e0 = d0 & 7;
                union { __bf16 h4[4]; uint2 u; } pk;
                if (which == 0) {
#pragma unroll
                    for (int r = 0; r < 4; ++r)
                        pk.h4[r] = (__bf16)(acc[mt][nt][r] * 0.18033688f); // 1/8 * log2(e)
                    int qt = tloc >> 5, fmt = (tloc >> 4) & 1;
                    *(uint2*)&Qb[((((bh * 32 + qt) * 2 + fmt) * 2 + kc) * 64 + ln) * 8 + e0] = pk.u;
                } else {
#pragma unroll
                    for (int r = 0; r < 4; ++r)
                        pk.h4[r] = (__bf16)acc[mt][nt][r];
                    int ktt = tloc >> 6, fnt = (tloc >> 4) & 3;
                    *(uint2*)&Kb[((((bh * 16 + ktt) * 4 + fnt) * 2 + kc) * 64 + ln) * 8 + e0] = pk.u;
                }
            }
        }
    } else {
        gemm_mainloop<0>(A, B, m0, n0, tid, acc, lA, lB);
#pragma unroll
        for (int nt = 0; nt < 4; ++nt) {
            int col = n0 + wn + nt * 16 + lr;
            int c = col - 768;
            int hh = c >> 6, d = c & 63;
            int fnt = d >> 4;
#pragma unroll
            for (int mt = 0; mt < 4; ++mt) {
                int row0 = m0 + wm + mt * 16 + lg * 4;
                int bb = row0 >> 10, t0 = row0 & 1023;
                size_t bh = (size_t)bb * 6 + hh;
                int ktt = t0 >> 6, kc = (t0 >> 5) & 1, e0 = t0 & 7;
                int ln = (d & 15) + 16 * ((t0 >> 3) & 3);
                union { __bf16 h4[4]; uint2 u; } pk;
#pragma unroll
                for (int r = 0; r < 4; ++r)
                    pk.h4[r] = (__bf16)acc[mt][nt][r];
                *(uint2*)&Vb[((((bh * 16 + ktt) * 4 + fnt) * 2 + kc) * 64 + ln) * 8 + e0] = pk.u;
            }
        }
    }
}

// ---------------- proj GEMM: swapped orientation -> float4 stores + bias -------

__global__ __launch_bounds__(256) void k_gemm_proj(
    const unsigned short* __restrict__ A,
    const unsigned short* __restrict__ B,
    const float* __restrict__ bias, float* __restrict__ Out)
{
    __shared__ unsigned short lA[128][64];
    __shared__ unsigned short lB[128][64];

    const int tid = threadIdx.x;
    const int m0 = blockIdx.x * 128, n0 = blockIdx.y * 128;
    const int w = tid >> 6, lane = tid & 63;
    const int wm = (w >> 1) * 64, wn = (w & 1) * 64;
    const int lr = lane & 15, lg = lane >> 4;

    f32x4 acc[4][4];
#pragma unroll
    for (int i = 0; i < 4; i++)
#pragma unroll
        for (int j = 0; j < 4; j++) acc[i][j] = zero4();

    gemm_mainloop<1>(A, B, m0, n0, tid, acc, lA, lB);

#pragma unroll
    for (int mt = 0; mt < 4; ++mt) {
        int row = m0 + wm + mt * 16 + lr;
#pragma unroll
        for (int nt = 0; nt < 4; ++nt) {
            int col = n0 + wn + nt * 16 + lg * 4;
            f32x4 bv = *(const f32x4*)&bias[col];
            f32x4 ov;
#pragma unroll
            for (int r = 0; r < 4; ++r) ov[r] = acc[mt][nt][r] + bv[r];
            *(f32x4*)&Out[(size_t)row * 384 + col] = ov;
        }
    }
}

// ---------------- flash attention, fixed-max (exp2), LDS-staged shared K/V ------
// Block = 1 bh, 4 waves = qtiles {4g..4g+3}. K/V tiles DMA'd via global_load_lds
// (double-buffered, fragment-major -> all LDS accesses linear & conflict-free).

template <int NTM, bool MASK>
static DEV void attn_tile(
    const unsigned short* lKt, const unsigned short* lVt, unsigned short* lPw,
    const bf16x8 (&qf)[2][2], f32x4 (&o)[2][4], float (&ls)[2],
    int kt, int qw, int lane)
{
    constexpr int KCM = NTM / 2;
    const int lr = lane & 15, lg = lane >> 4;

    bf16x8 kf[NTM][2];
#pragma unroll
    for (int nt = 0; nt < NTM; ++nt)
#pragma unroll
        for (int kc = 0; kc < 2; ++kc)
            kf[nt][kc] = *(const bf16x8*)&lKt[(nt * 2 + kc) * 512 + lane * 8];

    bf16x8 vf[4][KCM];
#pragma unroll
    for (int nt = 0; nt < 4; ++nt)
#pragma unroll
        for (int kc = 0; kc < KCM; ++kc)
            vf[nt][kc] = *(const bf16x8*)&lVt[(nt * 2 + kc) * 512 + lane * 8];

    // S^T = K * Q^T : lane holds q = mt*16+lr, k = nt*16+lg*4+r
    f32x4 st[2][NTM];
#pragma unroll
    for (int mt = 0; mt < 2; ++mt)
#pragma unroll
        for (int nt = 0; nt < NTM; ++nt) st[mt][nt] = zero4();

#pragma unroll
    for (int kc = 0; kc < 2; ++kc)
#pragma unroll
        for (int mt = 0; mt < 2; ++mt)
#pragma unroll
            for (int nt = 0; nt < NTM; ++nt)
                st[mt][nt] = __builtin_amdgcn_mfma_f32_16x16x32_bf16(kf[nt][kc], qf[mt][kc], st[mt][nt], 0, 0, 0);

    // exp2 (fixed max), tree rowsum partials, pack bf16, write P in FRAGMENT layout
#pragma unroll
    for (int mt = 0; mt < 2; ++mt) {
#pragma unroll
        for (int nt = 0; nt < NTM; ++nt) {
            union { __bf16 hh[4]; uint2 u; } pk;
            float e[4];
#pragma unroll
            for (int r = 0; r < 4; ++r) {
                float ev = __builtin_amdgcn_exp2f(st[mt][nt][r]);
                if (MASK) {
                    int kg = kt * 64 + nt * 16 + lg * 4 + r;
                    int qg = qw + mt * 16 + lr;
                    if (kg > qg) ev = 0.f;
                }
                e[r] = ev;
                pk.hh[r] = (__bf16)ev;
            }
            ls[mt] += (e[0] + e[1]) + (e[2] + e[3]);
            // P[q][k] -> A-fragment slot: kc=nt>>1, lane'=lr+16*((nt&1)*2+(lg>>1)), e'=(lg&1)*4+r
            int ln2 = lr + 16 * ((nt & 1) * 2 + (lg >> 1));
            *(uint2*)&lPw[(mt * 2 + (nt >> 1)) * 512 + ln2 * 8 + (lg & 1) * 4] = pk.u;
        }
    }

    bf16x8 pf[2][KCM];
#pragma unroll
    for (int mt = 0; mt < 2; ++mt)
#pragma unroll
        for (int kc = 0; kc < KCM; ++kc)
            pf[mt][kc] = *(const bf16x8*)&lPw[(mt * 2 + kc) * 512 + lane * 8];

#pragma unroll
    for (int mt = 0; mt < 2; ++mt)
#pragma unroll
        for (int nt = 0; nt < 4; ++nt)
#pragma unroll
            for (int kc = 0; kc < KCM; ++kc)
                o[mt][nt] = __builtin_amdgcn_mfma_f32_16x16x32_bf16(pf[mt][kc], vf[nt][kc], o[mt][nt], 0, 0, 0);
}

__global__ __launch_bounds__(256, 3) void k_attn(
    const unsigned short* __restrict__ Qf,
    const unsigned short* __restrict__ Kf,
    const unsigned short* __restrict__ Vf,
    unsigned short* __restrict__ Y)
{
    __shared__ unsigned short lK[2][4096];
    __shared__ unsigned short lV[2][4096];
    __shared__ unsigned short lPf[4][2048];

    const int tid = threadIdx.x;
    const int w = tid >> 6, lane = tid & 63;
    const int lr = lane & 15, lg = lane >> 4;
    const int bh = blockIdx.x;
    const int g = 7 - blockIdx.y;            // heavy groups dispatched first
    const int qt = 4 * g + w;
    const int qw = qt * 32;
    const int nkt = qt / 2 + 1;
    const int nsteps = 2 * g + 2;
    const int b = bh / 6, h = bh - b * 6;

    const unsigned short* Kbh = Kf + (size_t)bh * 65536;
    const unsigned short* Vbh = Vf + (size_t)bh * 65536;

    bf16x8 qf[2][2];
#pragma unroll
    for (int mt = 0; mt < 2; ++mt)
#pragma unroll
        for (int kc = 0; kc < 2; ++kc)
            qf[mt][kc] = *(const bf16x8*)&Qf[((((size_t)bh * 32 + qt) * 2 + mt) * 2 + kc) * 512 + lane * 8];

    f32x4 o[2][4];
    float ls[2] = {0.f, 0.f};
#pragma unroll
    for (int mt = 0; mt < 2; ++mt)
#pragma unroll
        for (int nt = 0; nt < 4; ++nt) o[mt][nt] = zero4();

    // prologue stage: tile 0 -> buf 0 (each wave stages its 2KB of K and V)
#pragma unroll
    for (int i = 0; i < 2; ++i) {
        __builtin_amdgcn_global_load_lds(GL1(Kbh + (size_t)w * 1024 + i * 512 + lane * 8),
                                         LDS3(&lK[0][w * 1024 + i * 512]), 16, 0, 0);
        __builtin_amdgcn_global_load_lds(GL1(Vbh + (size_t)w * 1024 + i * 512 + lane * 8),
                                         LDS3(&lV[0][w * 1024 + i * 512]), 16, 0, 0);
    }

    for (int kt = 0; kt < nsteps; ++kt) {
        __syncthreads();   // drains vmcnt -> buf[kt&1] ready; lgkm -> prev reads done
        if (kt + 1 < nsteps) {
            int nb = (kt + 1) & 1;
#pragma unroll
            for (int i = 0; i < 2; ++i) {
                __builtin_amdgcn_global_load_lds(GL1(Kbh + (size_t)(kt + 1) * 4096 + w * 1024 + i * 512 + lane * 8),
                                                 LDS3(&lK[nb][w * 1024 + i * 512]), 16, 0, 0);
                __builtin_amdgcn_global_load_lds(GL1(Vbh + (size_t)(kt + 1) * 4096 + w * 1024 + i * 512 + lane * 8),
                                                 LDS3(&lV[nb][w * 1024 + i * 512]), 16, 0, 0);
            }
        }
        if (kt < nkt) {
            const unsigned short* lKt = lK[kt & 1];
            const unsigned short* lVt = lV[kt & 1];
            if (kt == nkt - 1) {
                if (qt & 1) attn_tile<4, true>(lKt, lVt, lPf[w], qf, o, ls, kt, qw, lane);
                else        attn_tile<2, true>(lKt, lVt, lPf[w], qf, o, ls, kt, qw, lane);
            } else {
                attn_tile<4, false>(lKt, lVt, lPf[w], qf, o, ls, kt, qw, lane);
            }
        }
    }

    // deferred row-sum reduction + output
    float inv[2];
#pragma unroll
    for (int mt = 0; mt < 2; ++mt) {
        float s = ls[mt];
        s += __shfl_xor(s, 16);
        s += __shfl_xor(s, 32);
        inv[mt] = 1.0f / s;
    }
#pragma unroll
    for (int mt = 0; mt < 2; ++mt) {
        float iv[4];
#pragma unroll
        for (int r = 0; r < 4; ++r) iv[r] = __shfl(inv[mt], lg * 4 + r);
#pragma unroll
        for (int nt = 0; nt < 4; ++nt)
#pragma unroll
            for (int r = 0; r < 4; ++r) {
                int qrow = qw + mt * 16 + lg * 4 + r;
                int col = h * 64 + nt * 16 + lr;
                Y[((size_t)b * 1024 + qrow) * 384 + col] = f2bf(o[mt][nt][r] * iv[r]);
            }
    }
}

// ---------------- launcher ----------------

extern "C" void kernel_launch(void* const* d_in, const int* in_sizes, int n_in,
                              void* d_out, int out_size, void* d_ws, size_t ws_size,
                              hipStream_t stream)
{
    const float* x  = (const float*)d_in[0];
    const float* Wa = (const float*)d_in[1];
    const float* Wp = (const float*)d_in[2];
    const float* bp = (const float*)d_in[3];
    float* out = (float*)d_out;

    char* ws = (char*)d_ws;
    unsigned short* xb  = (unsigned short*)(ws);              // 25165824 B; reused as Y after attn
    unsigned short* WaT = (unsigned short*)(ws + 25165824);   // 884736 B
    unsigned short* WpT = (unsigned short*)(ws + 26050560);   // 294912 B
    unsigned short* Qb  = (unsigned short*)(ws + 26345472);   // 25165824 B (fragment-major)
    unsigned short* Kb  = (unsigned short*)(ws + 51511296);   // 25165824 B (fragment-major)
    unsigned short* Vtb = (unsigned short*)(ws + 76677120);   // 25165824 B (fragment-major)

    k_prep<<<14592, 256, 0, stream>>>(x, xb, Wa, WaT, Wp, WpT);
    k_gemm_qkv<<<dim3(256, 9), 256, 0, stream>>>(xb, WaT, Qb, Kb, Vtb);
    k_attn<<<dim3(192, 8), 256, 0, stream>>>(Qb, Kb, Vtb, xb);
    k_gemm_proj<<<dim3(256, 3), 256, 0, stream>>>(xb, WpT, bp, out);
}